// Round 1
// 259.148 us; speedup vs baseline: 1.0143x; 1.0143x over previous
//
#include <hip/hip_runtime.h>
#include <math.h>

#define MN_EPS 1e-4f
#define MN_MAXRPB 64   // max rows per block in the stats stripe (R/G = 32 here)

typedef float f4v __attribute__((ext_vector_type(4)));

__device__ inline void f4add(float4& a, const float4& b) {
    a.x += b.x; a.y += b.y; a.z += b.z; a.w += b.w;
}

// ---------------------------------------------------------------------------
// Kernel 1: per-block partial per-channel sum/sumsq over a 32-row stripe.
// Mask is staged and COMPACTED into an LDS index list of valid rows, so the
// accumulation loop issues unconditional, independent float4 loads over valid
// rows only. Regular (caching) loads ON PURPOSE: these y lines should stay
// L3-resident so mn_apply's re-read hits L3 instead of HBM.
// ---------------------------------------------------------------------------
__global__ void __launch_bounds__(256) mn_stats(
    const float4* __restrict__ y4, const int* __restrict__ mask,
    float4* __restrict__ pSum, float4* __restrict__ pSq,
    float* __restrict__ pCnt, int rowsPerBlock, int C4)
{
    __shared__ int sFlag[MN_MAXRPB];
    __shared__ int sIdx[MN_MAXRPB];
    __shared__ int sNum;
    const int tid = threadIdx.x;
    const int b = blockIdx.x;
    const long r0 = (long)b * rowsPerBlock;

    for (int t = tid; t < rowsPerBlock; t += 256)
        sFlag[t] = (mask[r0 + t] > 0) ? 1 : 0;
    __syncthreads();
    if (tid == 0) {
        int n = 0;
        for (int i = 0; i < rowsPerBlock; ++i)
            if (sFlag[i]) sIdx[n++] = i;
        sNum = n;
    }
    __syncthreads();
    const int nv = sNum;

    float4 s = make_float4(0.f, 0.f, 0.f, 0.f);
    float4 q = make_float4(0.f, 0.f, 0.f, 0.f);
    #pragma unroll 4
    for (int j = 0; j < nv; ++j) {
        const float4 v = y4[(r0 + sIdx[j]) * C4 + tid];
        s.x += v.x; s.y += v.y; s.z += v.z; s.w += v.w;
        q.x = fmaf(v.x, v.x, q.x);
        q.y = fmaf(v.y, v.y, q.y);
        q.z = fmaf(v.z, v.z, q.z);
        q.w = fmaf(v.w, v.w, q.w);
    }
    pSum[(long)b * C4 + tid] = s;
    pSq [(long)b * C4 + tid] = q;
    if (tid == 0) pCnt[b] = (float)nv;
}

// ---------------------------------------------------------------------------
// Kernel 2: one block per float4-of-channels (grid = C4). 256 threads stripe
// over the P partials, LDS tree-reduce, then thread 0 computes the fused
// affine coefficients a[c] = gamma/(std+eps), b[c] = beta - mean*a.
// ---------------------------------------------------------------------------
__global__ void __launch_bounds__(256) mn_finalize(
    const float4* __restrict__ pSum4, const float4* __restrict__ pSq4,
    const float* __restrict__ pCnt,
    const float4* __restrict__ gamma4, const float4* __restrict__ beta4,
    float4* __restrict__ aArr4, float4* __restrict__ bArr4, int P, int C4)
{
    __shared__ float4 sS[256];
    __shared__ float4 sQ[256];
    __shared__ float  sN[256];
    const int tid = threadIdx.x;
    const int c4 = blockIdx.x;

    float4 s = make_float4(0.f, 0.f, 0.f, 0.f);
    float4 q = make_float4(0.f, 0.f, 0.f, 0.f);
    float  n = 0.f;
    for (int p = tid; p < P; p += 256) {
        f4add(s, pSum4[(size_t)p * C4 + c4]);
        f4add(q, pSq4 [(size_t)p * C4 + c4]);
        n += pCnt[p];
    }
    sS[tid] = s; sQ[tid] = q; sN[tid] = n;
    __syncthreads();
    for (int off = 128; off > 0; off >>= 1) {
        if (tid < off) {
            f4add(sS[tid], sS[tid + off]);
            f4add(sQ[tid], sQ[tid + off]);
            sN[tid] += sN[tid + off];
        }
        __syncthreads();
    }
    if (tid == 0) {
        const float nn = sN[0];
        const float4 S = sS[0];
        const float4 Q = sQ[0];
        const float4 G = gamma4[c4];
        const float4 Bt = beta4[c4];
        float4 A, Bo;
        {
            const float mean = S.x / nn;
            const float var = fmaxf((Q.x - S.x * S.x / nn) / (nn - 1.0f), 0.0f);
            A.x = G.x / (sqrtf(var) + MN_EPS);
            Bo.x = Bt.x - mean * A.x;
        }
        {
            const float mean = S.y / nn;
            const float var = fmaxf((Q.y - S.y * S.y / nn) / (nn - 1.0f), 0.0f);
            A.y = G.y / (sqrtf(var) + MN_EPS);
            Bo.y = Bt.y - mean * A.y;
        }
        {
            const float mean = S.z / nn;
            const float var = fmaxf((Q.z - S.z * S.z / nn) / (nn - 1.0f), 0.0f);
            A.z = G.z / (sqrtf(var) + MN_EPS);
            Bo.z = Bt.z - mean * A.z;
        }
        {
            const float mean = S.w / nn;
            const float var = fmaxf((Q.w - S.w * S.w / nn) / (nn - 1.0f), 0.0f);
            A.w = G.w / (sqrtf(var) + MN_EPS);
            Bo.w = Bt.w - mean * A.w;
        }
        aArr4[c4] = A;
        bArr4[c4] = Bo;
    }
}

// ---------------------------------------------------------------------------
// Kernel 3: out[r][c] = mask[r] ? a[c]*y[r][c]+b[c] : y[r][c]
// Changes this round:
//   - NONTEMPORAL y loads + out stores: out (134 MB) is write-once and y is
//     dead after this kernel; no-allocate streaming keeps the stats-warmed
//     valid rows of y resident in L3 so the read half hits cache.
//   - 2 rows per grid-stride iteration: deeper independent load/store
//     pipelining per wave.
// ---------------------------------------------------------------------------
__global__ void __launch_bounds__(256) mn_apply(
    const f4v* __restrict__ y4, const int* __restrict__ mask,
    const f4v* __restrict__ aArr4, const f4v* __restrict__ bArr4,
    f4v* __restrict__ out4, int R, int C4)
{
    const int tid = threadIdx.x;
    const f4v A = aArr4[tid];
    const f4v Bv = bArr4[tid];
    const int stride = gridDim.x * 2;
    int r = blockIdx.x * 2;
    for (; r + 1 < R; r += stride) {
        const long i0 = (long)r * C4 + tid;
        const long i1 = i0 + C4;
        const int m0 = mask[r];
        const int m1 = mask[r + 1];
        f4v v0 = __builtin_nontemporal_load(y4 + i0);
        f4v v1 = __builtin_nontemporal_load(y4 + i1);
        f4v o0, o1;
        if (m0 > 0) {
            o0.x = fmaf(A.x, v0.x, Bv.x);
            o0.y = fmaf(A.y, v0.y, Bv.y);
            o0.z = fmaf(A.z, v0.z, Bv.z);
            o0.w = fmaf(A.w, v0.w, Bv.w);
        } else {
            o0 = v0;
        }
        if (m1 > 0) {
            o1.x = fmaf(A.x, v1.x, Bv.x);
            o1.y = fmaf(A.y, v1.y, Bv.y);
            o1.z = fmaf(A.z, v1.z, Bv.z);
            o1.w = fmaf(A.w, v1.w, Bv.w);
        } else {
            o1 = v1;
        }
        __builtin_nontemporal_store(o0, out4 + i0);
        __builtin_nontemporal_store(o1, out4 + i1);
    }
    if (r < R) {  // tail for odd R (not hit at R=32768, kept for generality)
        const long i0 = (long)r * C4 + tid;
        f4v v0 = __builtin_nontemporal_load(y4 + i0);
        f4v o0;
        if (mask[r] > 0) {
            o0.x = fmaf(A.x, v0.x, Bv.x);
            o0.y = fmaf(A.y, v0.y, Bv.y);
            o0.z = fmaf(A.z, v0.z, Bv.z);
            o0.w = fmaf(A.w, v0.w, Bv.w);
        } else {
            o0 = v0;
        }
        __builtin_nontemporal_store(o0, out4 + i0);
    }
}

extern "C" void kernel_launch(void* const* d_in, const int* in_sizes, int n_in,
                              void* d_out, int out_size, void* d_ws, size_t ws_size,
                              hipStream_t stream)
{
    const float* y     = (const float*)d_in[0];
    const int*   mask  = (const int*)  d_in[1];
    const float* gamma = (const float*)d_in[2];
    const float* beta  = (const float*)d_in[3];
    float* out = (float*)d_out;

    const int R  = in_sizes[1];   // B*T (mask element count)
    const int C  = in_sizes[2];   // channels (gamma element count)
    const int C4 = C / 4;         // 256 for C=1024

    // Largest P <= 1024 that divides R, keeps stripe <= MN_MAXRPB, fits ws.
    int P = 1024;
    while (P > 1) {
        const size_t need = ((size_t)2 * P * C + P + 2 * C) * sizeof(float);
        if (need <= ws_size && (R % P) == 0 && (R / P) <= MN_MAXRPB) break;
        P >>= 1;
    }
    const int rowsPerBlock = R / P;

    float* w    = (float*)d_ws;
    float* pSum = w;
    float* pSq  = pSum + (size_t)P * C;
    float* pCnt = pSq  + (size_t)P * C;
    float* aArr = pCnt + P;
    float* bArr = aArr + C;

    mn_stats<<<P, C4, 0, stream>>>((const float4*)y, mask,
                                   (float4*)pSum, (float4*)pSq, pCnt,
                                   rowsPerBlock, C4);

    mn_finalize<<<C4, 256, 0, stream>>>((const float4*)pSum, (const float4*)pSq,
                                        pCnt, (const float4*)gamma,
                                        (const float4*)beta,
                                        (float4*)aArr, (float4*)bArr, P, C4);

    mn_apply<<<2048, C4, 0, stream>>>((const f4v*)y, mask,
                                      (const f4v*)aArr, (const f4v*)bArr,
                                      (f4v*)out, R, C4);
}

// Round 3
// 253.350 us; speedup vs baseline: 1.0376x; 1.0229x over previous
//
#include <hip/hip_runtime.h>
#include <math.h>

#define MN_EPS 1e-4f
#define MN_MAXRPB 64   // max rows per block in the stats stripe (R/P = 64 at P=512)

typedef float f4v __attribute__((ext_vector_type(4)));

__device__ inline void f4add(float4& a, const float4& b) {
    a.x += b.x; a.y += b.y; a.z += b.z; a.w += b.w;
}

__device__ inline f4v mn_fma4(const f4v A, const f4v v, const f4v B) {
    f4v o;
    o.x = fmaf(A.x, v.x, B.x);
    o.y = fmaf(A.y, v.y, B.y);
    o.z = fmaf(A.z, v.z, B.z);
    o.w = fmaf(A.w, v.w, B.w);
    return o;
}

// ---------------------------------------------------------------------------
// Kernel 1: per-block partial per-channel sum/sumsq over a 64-row stripe.
// Mask is staged and COMPACTED into an LDS index list of valid rows, so the
// accumulation loop issues unconditional, independent float4 loads over valid
// rows only. Regular (caching) loads ON PURPOSE: these y lines should stay
// L3-resident so mn_apply's re-read hits L3 instead of HBM.
// P halved to 512 this round: halves partial-array write traffic and
// finalize's (8x line-overfetched) re-read, at 2 blocks/CU occupancy which
// still keeps ~32 KB of loads in flight per CU (>3x the ~9 KB needed to
// saturate HBM at ~900 cy miss latency).
// ---------------------------------------------------------------------------
__global__ void __launch_bounds__(256) mn_stats(
    const float4* __restrict__ y4, const int* __restrict__ mask,
    float4* __restrict__ pSum, float4* __restrict__ pSq,
    float* __restrict__ pCnt, int rowsPerBlock, int C4)
{
    __shared__ int sFlag[MN_MAXRPB];
    __shared__ int sIdx[MN_MAXRPB];
    __shared__ int sNum;
    const int tid = threadIdx.x;
    const int b = blockIdx.x;
    const long r0 = (long)b * rowsPerBlock;

    for (int t = tid; t < rowsPerBlock; t += 256)
        sFlag[t] = (mask[r0 + t] > 0) ? 1 : 0;
    __syncthreads();
    if (tid == 0) {
        int n = 0;
        for (int i = 0; i < rowsPerBlock; ++i)
            if (sFlag[i]) sIdx[n++] = i;
        sNum = n;
    }
    __syncthreads();
    const int nv = sNum;

    float4 s = make_float4(0.f, 0.f, 0.f, 0.f);
    float4 q = make_float4(0.f, 0.f, 0.f, 0.f);
    #pragma unroll 4
    for (int j = 0; j < nv; ++j) {
        const float4 v = y4[(r0 + sIdx[j]) * C4 + tid];
        s.x += v.x; s.y += v.y; s.z += v.z; s.w += v.w;
        q.x = fmaf(v.x, v.x, q.x);
        q.y = fmaf(v.y, v.y, q.y);
        q.z = fmaf(v.z, v.z, q.z);
        q.w = fmaf(v.w, v.w, q.w);
    }
    pSum[(long)b * C4 + tid] = s;
    pSq [(long)b * C4 + tid] = q;
    if (tid == 0) pCnt[b] = (float)nv;
}

// ---------------------------------------------------------------------------
// Kernel 2: one block per float4-of-channels (grid = C4). 256 threads stripe
// over the P partials, LDS tree-reduce, then thread 0 computes the fused
// affine coefficients a[c] = gamma/(std+eps), b[c] = beta - mean*a.
// With P=512 each thread does 2 strided iterations; total unique partial
// data is 8.4 MB (was 16.8), cutting the L3 over-fetch proportionally.
// ---------------------------------------------------------------------------
__global__ void __launch_bounds__(256) mn_finalize(
    const float4* __restrict__ pSum4, const float4* __restrict__ pSq4,
    const float* __restrict__ pCnt,
    const float4* __restrict__ gamma4, const float4* __restrict__ beta4,
    float4* __restrict__ aArr4, float4* __restrict__ bArr4, int P, int C4)
{
    __shared__ float4 sS[256];
    __shared__ float4 sQ[256];
    __shared__ float  sN[256];
    const int tid = threadIdx.x;
    const int c4 = blockIdx.x;

    float4 s = make_float4(0.f, 0.f, 0.f, 0.f);
    float4 q = make_float4(0.f, 0.f, 0.f, 0.f);
    float  n = 0.f;
    for (int p = tid; p < P; p += 256) {
        f4add(s, pSum4[(size_t)p * C4 + c4]);
        f4add(q, pSq4 [(size_t)p * C4 + c4]);
        n += pCnt[p];
    }
    sS[tid] = s; sQ[tid] = q; sN[tid] = n;
    __syncthreads();
    for (int off = 128; off > 0; off >>= 1) {
        if (tid < off) {
            f4add(sS[tid], sS[tid + off]);
            f4add(sQ[tid], sQ[tid + off]);
            sN[tid] += sN[tid + off];
        }
        __syncthreads();
    }
    if (tid == 0) {
        const float nn = sN[0];
        const float4 S = sS[0];
        const float4 Q = sQ[0];
        const float4 G = gamma4[c4];
        const float4 Bt = beta4[c4];
        float4 A, Bo;
        {
            const float mean = S.x / nn;
            const float var = fmaxf((Q.x - S.x * S.x / nn) / (nn - 1.0f), 0.0f);
            A.x = G.x / (sqrtf(var) + MN_EPS);
            Bo.x = Bt.x - mean * A.x;
        }
        {
            const float mean = S.y / nn;
            const float var = fmaxf((Q.y - S.y * S.y / nn) / (nn - 1.0f), 0.0f);
            A.y = G.y / (sqrtf(var) + MN_EPS);
            Bo.y = Bt.y - mean * A.y;
        }
        {
            const float mean = S.z / nn;
            const float var = fmaxf((Q.z - S.z * S.z / nn) / (nn - 1.0f), 0.0f);
            A.z = G.z / (sqrtf(var) + MN_EPS);
            Bo.z = Bt.z - mean * A.z;
        }
        {
            const float mean = S.w / nn;
            const float var = fmaxf((Q.w - S.w * S.w / nn) / (nn - 1.0f), 0.0f);
            A.w = G.w / (sqrtf(var) + MN_EPS);
            Bo.w = Bt.w - mean * A.w;
        }
        aArr4[c4] = A;
        bArr4[c4] = Bo;
    }
}

// ---------------------------------------------------------------------------
// Kernel 3: out[r][c] = mask[r] ? a[c]*y[r][c]+b[c] : y[r][c]
//   - NONTEMPORAL y loads + out stores: out (134 MB) is write-once and y is
//     dead after this kernel; no-allocate streaming keeps the stats-warmed
//     valid rows of y resident in L3 so the read half hits cache
//     (L3 budget during apply: 67 MB valid-y + 67 MB invalid-y + ~15 MB
//     partials < 256 MB, only because out never allocates).
//   - 4 rows per grid-stride iteration this round: 64 B of independent loads
//     in flight per thread for deeper latency tolerance on the HBM half.
// ---------------------------------------------------------------------------
__global__ void __launch_bounds__(256) mn_apply(
    const f4v* __restrict__ y4, const int* __restrict__ mask,
    const f4v* __restrict__ aArr4, const f4v* __restrict__ bArr4,
    f4v* __restrict__ out4, int R, int C4)
{
    const int tid = threadIdx.x;
    const f4v A = aArr4[tid];
    const f4v Bv = bArr4[tid];
    const int Rmain = R & ~3;          // multiple of 4
    const int stride = gridDim.x * 4;
    for (int r = blockIdx.x * 4; r < Rmain; r += stride) {
        const long i0 = (long)r * C4 + tid;
        const int m0 = mask[r];
        const int m1 = mask[r + 1];
        const int m2 = mask[r + 2];
        const int m3 = mask[r + 3];
        f4v v0 = __builtin_nontemporal_load(y4 + i0);
        f4v v1 = __builtin_nontemporal_load(y4 + i0 + C4);
        f4v v2 = __builtin_nontemporal_load(y4 + i0 + 2 * (long)C4);
        f4v v3 = __builtin_nontemporal_load(y4 + i0 + 3 * (long)C4);
        f4v o0 = (m0 > 0) ? mn_fma4(A, v0, Bv) : v0;
        f4v o1 = (m1 > 0) ? mn_fma4(A, v1, Bv) : v1;
        f4v o2 = (m2 > 0) ? mn_fma4(A, v2, Bv) : v2;
        f4v o3 = (m3 > 0) ? mn_fma4(A, v3, Bv) : v3;
        __builtin_nontemporal_store(o0, out4 + i0);
        __builtin_nontemporal_store(o1, out4 + i0 + C4);
        __builtin_nontemporal_store(o2, out4 + i0 + 2 * (long)C4);
        __builtin_nontemporal_store(o3, out4 + i0 + 3 * (long)C4);
    }
    // tail rows (R not multiple of 4): first (R-Rmain) blocks take one each
    const int rt = Rmain + blockIdx.x;
    if (rt < R) {
        const long i0 = (long)rt * C4 + tid;
        f4v v0 = __builtin_nontemporal_load(y4 + i0);
        f4v o0 = (mask[rt] > 0) ? mn_fma4(A, v0, Bv) : v0;
        __builtin_nontemporal_store(o0, out4 + i0);
    }
}

extern "C" void kernel_launch(void* const* d_in, const int* in_sizes, int n_in,
                              void* d_out, int out_size, void* d_ws, size_t ws_size,
                              hipStream_t stream)
{
    const float* y     = (const float*)d_in[0];
    const int*   mask  = (const int*)  d_in[1];
    const float* gamma = (const float*)d_in[2];
    const float* beta  = (const float*)d_in[3];
    float* out = (float*)d_out;

    const int R  = in_sizes[1];   // B*T (mask element count)
    const int C  = in_sizes[2];   // channels (gamma element count)
    const int C4 = C / 4;         // 256 for C=1024

    // Largest P <= 512 that divides R, keeps stripe <= MN_MAXRPB, fits ws.
    // P=512: halves partial traffic vs 1024 while stats keeps 2 blocks/CU.
    int P = 512;
    while (P > 1) {
        const size_t need = ((size_t)2 * P * C + P + 2 * C) * sizeof(float);
        if (need <= ws_size && (R % P) == 0 && (R / P) <= MN_MAXRPB) break;
        P >>= 1;
    }
    const int rowsPerBlock = R / P;

    float* w    = (float*)d_ws;
    float* pSum = w;
    float* pSq  = pSum + (size_t)P * C;
    float* pCnt = pSq  + (size_t)P * C;
    float* aArr = pCnt + P;
    float* bArr = aArr + C;

    mn_stats<<<P, C4, 0, stream>>>((const float4*)y, mask,
                                   (float4*)pSum, (float4*)pSq, pCnt,
                                   rowsPerBlock, C4);

    mn_finalize<<<C4, 256, 0, stream>>>((const float4*)pSum, (const float4*)pSq,
                                        pCnt, (const float4*)gamma,
                                        (const float4*)beta,
                                        (float4*)aArr, (float4*)bArr, P, C4);

    mn_apply<<<2048, C4, 0, stream>>>((const f4v*)y, mask,
                                      (const f4v*)aArr, (const f4v*)bArr,
                                      (f4v*)out, R, C4);
}

// Round 4
// 247.601 us; speedup vs baseline: 1.0616x; 1.0232x over previous
//
#include <hip/hip_runtime.h>
#include <math.h>

#define MN_EPS 1e-4f
#define MN_MAXRPB 128  // max rows per stats stripe (R/P = 128 at P=256)

typedef float f4v __attribute__((ext_vector_type(4)));

__device__ inline void f4add(float4& a, const float4& b) {
    a.x += b.x; a.y += b.y; a.z += b.z; a.w += b.w;
}

__device__ inline f4v mn_fma4(const f4v A, const f4v v, const f4v B) {
    f4v o;
    o.x = fmaf(A.x, v.x, B.x);
    o.y = fmaf(A.y, v.y, B.y);
    o.z = fmaf(A.z, v.z, B.z);
    o.w = fmaf(A.w, v.w, B.w);
    return o;
}

// ---------------------------------------------------------------------------
// Kernel 1: per-block partial per-channel sum/sumsq over a 128-row stripe.
// 512 threads/block = two 256-thread halves; half h owns rows
// [h*halfRows, (h+1)*halfRows) of the stripe, so P=256 partials (half the
// partial write + finalize re-read of P=512) at UNCHANGED 8 waves/CU memory-
// level parallelism (vs 4 waves/CU if we'd shrunk the grid at 256 threads).
// Mask compaction is wave-parallel this round: one 64-lane wave per half does
// __ballot + __popcll-prefix scatter into the LDS index list — replaces the
// serial 64-iter thread-0 loop that stalled the whole block (~0.5 us).
// Valid-row loads stay unconditional/independent; caching loads ON PURPOSE so
// the valid y rows are L3-resident for mn_apply's re-read.
// NOTE: assumes C4 <= 256 (LDS combine buffers) — true for this problem.
// ---------------------------------------------------------------------------
__global__ void __launch_bounds__(512) mn_stats(
    const float4* __restrict__ y4, const int* __restrict__ mask,
    float4* __restrict__ pSum, float4* __restrict__ pSq,
    float* __restrict__ pCnt, int rowsPerBlock, int C4)
{
    __shared__ int sIdx[2][64];
    __shared__ int sNum[2];
    __shared__ float4 sS[256];
    __shared__ float4 sQ[256];
    const int tid = threadIdx.x;
    const int half = tid / C4;            // 0 or 1
    const int ch = tid - half * C4;       // channel float4 index
    const int b = blockIdx.x;
    const long r0 = (long)b * rowsPerBlock;
    const int halfRows = (rowsPerBlock + 1) >> 1;   // <= 64 by MN_MAXRPB

    // Wave-ballot compaction: wave 0 handles half 0's rows, the first wave of
    // the upper half (tid in [C4, C4+64)) handles half 1's rows. Both are
    // wave-uniform entries (no divergent __ballot).
    if (tid < 64 || (tid >= C4 && tid < C4 + 64)) {
        const int h = (tid < 64) ? 0 : 1;
        const int lane = tid & 63;
        const int r = h * halfRows + lane;            // row within stripe
        const bool f = (lane < halfRows) && (r < rowsPerBlock)
                       && (mask[r0 + r] > 0);
        const unsigned long long bal = __ballot(f);
        if (f) sIdx[h][(int)__popcll(bal & ((1ull << lane) - 1ull))] = r;
        if (lane == 0) sNum[h] = (int)__popcll(bal);
    }
    __syncthreads();
    const int nv = sNum[half];

    float4 s = make_float4(0.f, 0.f, 0.f, 0.f);
    float4 q = make_float4(0.f, 0.f, 0.f, 0.f);
    #pragma unroll 4
    for (int j = 0; j < nv; ++j) {
        const float4 v = y4[(r0 + sIdx[half][j]) * C4 + ch];
        s.x += v.x; s.y += v.y; s.z += v.z; s.w += v.w;
        q.x = fmaf(v.x, v.x, q.x);
        q.y = fmaf(v.y, v.y, q.y);
        q.z = fmaf(v.z, v.z, q.z);
        q.w = fmaf(v.w, v.w, q.w);
    }

    // Combine the two halves in LDS, one partial row per block.
    if (half == 1) {
        sS[ch] = make_float4(s.x, s.y, s.z, s.w);
        sQ[ch] = make_float4(q.x, q.y, q.z, q.w);
    }
    __syncthreads();
    if (half == 0) {
        f4add(s, sS[ch]);
        f4add(q, sQ[ch]);
        pSum[(long)b * C4 + ch] = s;
        pSq [(long)b * C4 + ch] = q;
        if (ch == 0) pCnt[b] = (float)(sNum[0] + sNum[1]);
    }
}

// ---------------------------------------------------------------------------
// Kernel 2: one block per float4-of-channels (grid = C4). 256 threads stripe
// over the P partials (P=256 -> exactly one each), LDS tree-reduce, then
// thread 0 computes the fused affine coefficients a[c] = gamma/(std+eps),
// b[c] = beta - mean*a. Unique partial data now 2.1+2.1 MB.
// ---------------------------------------------------------------------------
__global__ void __launch_bounds__(256) mn_finalize(
    const float4* __restrict__ pSum4, const float4* __restrict__ pSq4,
    const float* __restrict__ pCnt,
    const float4* __restrict__ gamma4, const float4* __restrict__ beta4,
    float4* __restrict__ aArr4, float4* __restrict__ bArr4, int P, int C4)
{
    __shared__ float4 sS[256];
    __shared__ float4 sQ[256];
    __shared__ float  sN[256];
    const int tid = threadIdx.x;
    const int c4 = blockIdx.x;

    float4 s = make_float4(0.f, 0.f, 0.f, 0.f);
    float4 q = make_float4(0.f, 0.f, 0.f, 0.f);
    float  n = 0.f;
    for (int p = tid; p < P; p += 256) {
        f4add(s, pSum4[(size_t)p * C4 + c4]);
        f4add(q, pSq4 [(size_t)p * C4 + c4]);
        n += pCnt[p];
    }
    sS[tid] = s; sQ[tid] = q; sN[tid] = n;
    __syncthreads();
    for (int off = 128; off > 0; off >>= 1) {
        if (tid < off) {
            f4add(sS[tid], sS[tid + off]);
            f4add(sQ[tid], sQ[tid + off]);
            sN[tid] += sN[tid + off];
        }
        __syncthreads();
    }
    if (tid == 0) {
        const float nn = sN[0];
        const float4 S = sS[0];
        const float4 Q = sQ[0];
        const float4 G = gamma4[c4];
        const float4 Bt = beta4[c4];
        float4 A, Bo;
        {
            const float mean = S.x / nn;
            const float var = fmaxf((Q.x - S.x * S.x / nn) / (nn - 1.0f), 0.0f);
            A.x = G.x / (sqrtf(var) + MN_EPS);
            Bo.x = Bt.x - mean * A.x;
        }
        {
            const float mean = S.y / nn;
            const float var = fmaxf((Q.y - S.y * S.y / nn) / (nn - 1.0f), 0.0f);
            A.y = G.y / (sqrtf(var) + MN_EPS);
            Bo.y = Bt.y - mean * A.y;
        }
        {
            const float mean = S.z / nn;
            const float var = fmaxf((Q.z - S.z * S.z / nn) / (nn - 1.0f), 0.0f);
            A.z = G.z / (sqrtf(var) + MN_EPS);
            Bo.z = Bt.z - mean * A.z;
        }
        {
            const float mean = S.w / nn;
            const float var = fmaxf((Q.w - S.w * S.w / nn) / (nn - 1.0f), 0.0f);
            A.w = G.w / (sqrtf(var) + MN_EPS);
            Bo.w = Bt.w - mean * A.w;
        }
        aArr4[c4] = A;
        bArr4[c4] = Bo;
    }
}

// ---------------------------------------------------------------------------
// Kernel 3 (UNCHANGED this round — clean A/B on the stats path):
// out[r][c] = mask[r] ? a[c]*y[r][c]+b[c] : y[r][c]
//   - NONTEMPORAL y loads + out stores: out (134 MB) is write-once and y is
//     dead after this kernel; no-allocate streaming keeps the stats-warmed
//     valid rows of y resident in L3 so the read half hits cache.
//   - 4 rows per grid-stride iteration: 64 B of independent loads in flight
//     per thread for latency tolerance on the HBM (invalid-row) half.
// ---------------------------------------------------------------------------
__global__ void __launch_bounds__(256) mn_apply(
    const f4v* __restrict__ y4, const int* __restrict__ mask,
    const f4v* __restrict__ aArr4, const f4v* __restrict__ bArr4,
    f4v* __restrict__ out4, int R, int C4)
{
    const int tid = threadIdx.x;
    const f4v A = aArr4[tid];
    const f4v Bv = bArr4[tid];
    const int Rmain = R & ~3;          // multiple of 4
    const int stride = gridDim.x * 4;
    for (int r = blockIdx.x * 4; r < Rmain; r += stride) {
        const long i0 = (long)r * C4 + tid;
        const int m0 = mask[r];
        const int m1 = mask[r + 1];
        const int m2 = mask[r + 2];
        const int m3 = mask[r + 3];
        f4v v0 = __builtin_nontemporal_load(y4 + i0);
        f4v v1 = __builtin_nontemporal_load(y4 + i0 + C4);
        f4v v2 = __builtin_nontemporal_load(y4 + i0 + 2 * (long)C4);
        f4v v3 = __builtin_nontemporal_load(y4 + i0 + 3 * (long)C4);
        f4v o0 = (m0 > 0) ? mn_fma4(A, v0, Bv) : v0;
        f4v o1 = (m1 > 0) ? mn_fma4(A, v1, Bv) : v1;
        f4v o2 = (m2 > 0) ? mn_fma4(A, v2, Bv) : v2;
        f4v o3 = (m3 > 0) ? mn_fma4(A, v3, Bv) : v3;
        __builtin_nontemporal_store(o0, out4 + i0);
        __builtin_nontemporal_store(o1, out4 + i0 + C4);
        __builtin_nontemporal_store(o2, out4 + i0 + 2 * (long)C4);
        __builtin_nontemporal_store(o3, out4 + i0 + 3 * (long)C4);
    }
    // tail rows (R not multiple of 4): first (R-Rmain) blocks take one each
    const int rt = Rmain + blockIdx.x;
    if (rt < R) {
        const long i0 = (long)rt * C4 + tid;
        f4v v0 = __builtin_nontemporal_load(y4 + i0);
        f4v o0 = (mask[rt] > 0) ? mn_fma4(A, v0, Bv) : v0;
        __builtin_nontemporal_store(o0, out4 + i0);
    }
}

extern "C" void kernel_launch(void* const* d_in, const int* in_sizes, int n_in,
                              void* d_out, int out_size, void* d_ws, size_t ws_size,
                              hipStream_t stream)
{
    const float* y     = (const float*)d_in[0];
    const int*   mask  = (const int*)  d_in[1];
    const float* gamma = (const float*)d_in[2];
    const float* beta  = (const float*)d_in[3];
    float* out = (float*)d_out;

    const int R  = in_sizes[1];   // B*T (mask element count)
    const int C  = in_sizes[2];   // channels (gamma element count)
    const int C4 = C / 4;         // 256 for C=1024

    // Largest P <= 256 that divides R, keeps stripe <= MN_MAXRPB, fits ws.
    // P=256: half the partial traffic of P=512, with 512-thread stats blocks
    // preserving 8 waves/CU of memory-level parallelism.
    int P = 256;
    while (P > 1) {
        const size_t need = ((size_t)2 * P * C + P + 2 * C) * sizeof(float);
        if (need <= ws_size && (R % P) == 0 && (R / P) <= MN_MAXRPB) break;
        P >>= 1;
    }
    const int rowsPerBlock = R / P;

    float* w    = (float*)d_ws;
    float* pSum = w;
    float* pSq  = pSum + (size_t)P * C;
    float* pCnt = pSq  + (size_t)P * C;
    float* aArr = pCnt + P;
    float* bArr = aArr + C;

    mn_stats<<<P, 2 * C4, 0, stream>>>((const float4*)y, mask,
                                       (float4*)pSum, (float4*)pSq, pCnt,
                                       rowsPerBlock, C4);

    mn_finalize<<<C4, 256, 0, stream>>>((const float4*)pSum, (const float4*)pSq,
                                        pCnt, (const float4*)gamma,
                                        (const float4*)beta,
                                        (float4*)aArr, (float4*)bArr, P, C4);

    mn_apply<<<2048, C4, 0, stream>>>((const f4v*)y, mask,
                                      (const f4v*)aArr, (const f4v*)bArr,
                                      (f4v*)out, R, C4);
}